// Round 9
// baseline (174.902 us; speedup 1.0000x reference)
//
#include <hip/hip_runtime.h>
#include <hip/hip_cooperative_groups.h>
#include <math.h>

namespace cg = cooperative_groups;

#define N1 10000
#define N2 5000
#define DIN 30
#define DZ 32
#define N1P 10016   // 313*32
#define N2P 5024    // 157*32
#define NTJ 313     // j-tiles of 32
#define NTI 157     // i-tiles of 32
#define NCHB 6      // partial buffers per i-tile
#define CTILES 14   // j-tiles per wave-chunk (24*14=336 >= 313)
#define NRED 16     // landmark-reduction virtual blocks
#define NPREP 252   // 157 + 79 + 16 virtual prep blocks
#define NATTN (NTI * NCHB)  // 942
#define NFIN 625
#define GRID_MAX 942

// byte offsets in ws (16B aligned)
#define OFFB_K    0u        // bf16 K[N1P][32]
#define OFFB_FF   641024u   // bf16 F_frag[(t,frag,lane)][8]  (MFMA B-frag order)
#define OFFB_Q    1282048u  // bf16 Qs[N2P][32]  (pre-scaled by log2e/sqrt(32))
#define OFFB_ZP   1603584u  // f32 Zpart[6][N2P]
#define OFFB_M1   1724160u  // bf16 M1part[6][N2P][32]
#define OFFB_RP   3653376u  // f32 red_part[16][66]

typedef __bf16 bf16x8 __attribute__((ext_vector_type(8)));
typedef float f32x16 __attribute__((ext_vector_type(16)));
typedef unsigned u32x2 __attribute__((ext_vector_type(2)));

union W4 { unsigned w[4]; bf16x8 v; };

struct SPrep { float sX[64 * DIN]; __bf16 sF[64][33]; };
struct SRed  { float sb0[8][32]; float sb1[8][32]; float sd[8]; };
struct SAttn { float sZ[4][32]; float sM[4][32][32]; };
struct SFin  { float s_a[8][DZ]; float s_t1[8][DZ]; float s_t2[8][DZ];
               float s_rsum[DZ]; float s_dv[DZ]; float s_r0[DZ];
               float s_r1[DZ]; float s_tmp[DZ]; float s_ds[1]; };
union SMem { SPrep prep; SRed red; SAttn attn; SFin fin; };

__device__ __forceinline__ float softplus_f(float x) {
  return fmaxf(x, 0.f) + log1pf(__expf(-fabsf(x)));
}
__device__ __forceinline__ unsigned pack2bf(float a, float b) {
  union { __bf16 h[2]; unsigned u; } x;
  x.h[0] = (__bf16)a; x.h[1] = (__bf16)b; return x.u;
}

// ---------------- phase bodies (shared by fused + standalone) ----------------

__device__ __forceinline__ void do_prep(SMem& sm, int bid, int tid,
    const float* __restrict__ lm_X, const float* __restrict__ lm_Y,
    const float* __restrict__ tg_X, const float* __restrict__ lm_delay,
    const float* __restrict__ Wq, const float* __restrict__ Wk,
    const float* __restrict__ g1p, const float* __restrict__ ap,
    const float* __restrict__ bp,
    __bf16* __restrict__ Kb, __bf16* __restrict__ Ff,
    __bf16* __restrict__ Qb, float* __restrict__ rp) {
  if (bid < 157) {
    const int j0 = bid * 64;
    for (int idx = tid; idx < 64 * DIN; idx += 256) {
      const int g = j0 * DIN + idx;
      sm.prep.sX[idx] = (g < N1 * DIN) ? lm_X[g] : 0.f;
    }
    const int z = tid & 31, jl = tid >> 5;
    float wk[DIN];
#pragma unroll
    for (int k = 0; k < DIN; ++k) wk[k] = Wk[z * DIN + k];
    __syncthreads();
#pragma unroll
    for (int q8 = 0; q8 < 8; ++q8) {
      const int jj = jl + q8 * 8;
      const int j = j0 + jj;
      float s = 0.f;
#pragma unroll
      for (int k = 0; k < DIN; ++k) s = fmaf(sm.prep.sX[jj * DIN + k], wk[k], s);
      float fval;
      if (z < DIN) fval = sm.prep.sX[jj * DIN + z];
      else fval = (j < N1) ? lm_Y[j * 2 + (z - DIN)] : 0.f;
      if (j < N1P) Kb[j * DZ + z] = (__bf16)s;
      sm.prep.sF[jj][z] = (__bf16)fval;
    }
    __syncthreads();
    // F in MFMA B-fragment order: unit (t,frag,lane) holds
    // F[j = t*32 + frag*16 + (lane>>5)*8 + e][z = lane&31]
    const int tt = tid >> 7, frag = (tid >> 6) & 1, lane = tid & 63;
    const int li2 = lane & 31, hi2 = lane >> 5;
    const int tglob = 2 * bid + tt;
    if (tglob < NTJ) {
      const int jl2 = tt * 32 + frag * 16 + hi2 * 8;
      bf16x8 v;
#pragma unroll
      for (int e = 0; e < 8; ++e) v[e] = sm.prep.sF[jl2 + e][li2];
      *(bf16x8*)(Ff + ((size_t)(tglob * 2 + frag) * 64 + lane) * 8) = v;
    }
  } else if (bid < 236) {
    const int i0 = (bid - 157) * 64;
    for (int idx = tid; idx < 64 * DIN; idx += 256) {
      const int g = i0 * DIN + idx;
      sm.prep.sX[idx] = (g < N2 * DIN) ? tg_X[g] : 0.f;
    }
    const int z = tid & 31, il = tid >> 5;
    float wq[DIN];
#pragma unroll
    for (int k = 0; k < DIN; ++k) wq[k] = Wq[z * DIN + k];
    __syncthreads();
    const float sc = 0.17677669529663687f * 1.4426950408889634f;  // log2e/sqrt32
#pragma unroll
    for (int q8 = 0; q8 < 8; ++q8) {
      const int ii = il + q8 * 8;
      const int i = i0 + ii;
      float s = 0.f;
#pragma unroll
      for (int k = 0; k < DIN; ++k) s = fmaf(sm.prep.sX[ii * DIN + k], wq[k], s);
      if (i < N2P) Qb[i * DZ + z] = (__bf16)(s * sc);
    }
  } else if (bid < 236 + NRED) {
    const int b3 = bid - 236;
    const int z = tid & 31, jg = tid >> 5;
    const float a = ap[0], b = bp[0], g1 = g1p[0];
    float rs = 0.f, dv = 0.f, dss = 0.f;
    for (int j = b3 * 8 + jg; j < N1; j += NRED * 8) {
      float f = (z < DIN) ? lm_X[j * DIN + z] : lm_Y[j * 2 + (z - DIN)];
      float ds = __expf(-g1 * (a * lm_delay[j] + b));
      rs += f; dv += ds * f;
      if (z == 0) dss += ds;
    }
    sm.red.sb0[jg][z] = rs; sm.red.sb1[jg][z] = dv;
    if (z == 0) sm.red.sd[jg] = dss;
    __syncthreads();
    if (tid < 32) {
      float t0 = 0.f, t1 = 0.f;
#pragma unroll
      for (int g = 0; g < 8; ++g) { t0 += sm.red.sb0[g][tid]; t1 += sm.red.sb1[g][tid]; }
      rp[b3 * 66 + tid] = t0;
      rp[b3 * 66 + 32 + tid] = t1;
    } else if (tid == 32) {
      float t = 0.f;
#pragma unroll
      for (int g = 0; g < 8; ++g) t += sm.red.sd[g];
      rp[b3 * 66 + 64] = t;
    }
  }
}

__device__ __forceinline__ void do_attn(SMem& sm, int vb, int tid,
    const __bf16* __restrict__ Kb, const __bf16* __restrict__ Ff,
    const __bf16* __restrict__ Qb, float* __restrict__ Zp,
    __bf16* __restrict__ M1p) {
  const int it = vb / NCHB, cb = vb % NCHB;
  const int i0 = it * 32;
  const int lane = tid & 63, wid = tid >> 6;
  const int li = lane & 31, hi = lane >> 5;
  const int c = cb * 4 + wid;
  const int t0 = c * CTILES, t1 = min(t0 + CTILES, NTJ);
  const bf16x8 b0 = *(const bf16x8*)(Qb + (i0 + li) * DZ + hi * 8);
  const bf16x8 b1 = *(const bf16x8*)(Qb + (i0 + li) * DZ + 16 + hi * 8);
  float s1 = 0.f;
  f32x16 pacc = {0.f,0.f,0.f,0.f,0.f,0.f,0.f,0.f,0.f,0.f,0.f,0.f,0.f,0.f,0.f,0.f};
  for (int t = t0; t < t1; ++t) {
    const int jt = t * 32;
    bf16x8 a0 = *(const bf16x8*)(Kb + ((size_t)jt + li) * DZ + hi * 8);
    bf16x8 a1 = *(const bf16x8*)(Kb + ((size_t)jt + li) * DZ + 16 + hi * 8);
    bf16x8 f0 = *(const bf16x8*)(Ff + (size_t)t * 1024 + lane * 8);
    bf16x8 f1 = *(const bf16x8*)(Ff + (size_t)t * 1024 + 512 + lane * 8);
    f32x16 sacc = {0.f,0.f,0.f,0.f,0.f,0.f,0.f,0.f,0.f,0.f,0.f,0.f,0.f,0.f,0.f,0.f};
    sacc = __builtin_amdgcn_mfma_f32_32x32x16_bf16(a0, b0, sacc, 0, 0, 0);
    sacc = __builtin_amdgcn_mfma_f32_32x32x16_bf16(a1, b1, sacc, 0, 0, 0);
    unsigned u[8];
#pragma unroll
    for (int k2 = 0; k2 < 8; ++k2) {
      const float e0 = __builtin_amdgcn_exp2f(sacc[2 * k2]) - 1.f;
      const float e1 = __builtin_amdgcn_exp2f(sacc[2 * k2 + 1]) - 1.f;
      s1 += e0 + e1;
      u[k2] = pack2bf(e0, e1);
    }
    W4 A1, A2;
    u32x2 r01 = __builtin_amdgcn_permlane32_swap(u[0], u[2], false, false);
    u32x2 r23 = __builtin_amdgcn_permlane32_swap(u[1], u[3], false, false);
    u32x2 r45 = __builtin_amdgcn_permlane32_swap(u[4], u[6], false, false);
    u32x2 r67 = __builtin_amdgcn_permlane32_swap(u[5], u[7], false, false);
    A1.w[0] = r01[0]; A1.w[2] = r01[1];
    A1.w[1] = r23[0]; A1.w[3] = r23[1];
    A2.w[0] = r45[0]; A2.w[2] = r45[1];
    A2.w[1] = r67[0]; A2.w[3] = r67[1];
    pacc = __builtin_amdgcn_mfma_f32_32x32x16_bf16(A1.v, f0, pacc, 0, 0, 0);
    pacc = __builtin_amdgcn_mfma_f32_32x32x16_bf16(A2.v, f1, pacc, 0, 0, 0);
  }
  s1 += __shfl_xor(s1, 32, 64);
  if (hi == 0) sm.attn.sZ[wid][li] = s1;
#pragma unroll
  for (int r = 0; r < 16; ++r) {
    const int irow = (r & 3) + 8 * (r >> 2) + 4 * hi;
    sm.attn.sM[wid][irow][li] = pacc[r];
  }
  __syncthreads();
  if (tid < 32)
    Zp[cb * N2P + i0 + tid] = sm.attn.sZ[0][tid] + sm.attn.sZ[1][tid]
                            + sm.attn.sZ[2][tid] + sm.attn.sZ[3][tid];
#pragma unroll
  for (int v = 0; v < 4; ++v) {
    const int idx = v * 256 + tid;
    const int row = idx >> 5, z = idx & 31;
    float m = sm.attn.sM[0][row][z] + sm.attn.sM[1][row][z]
            + sm.attn.sM[2][row][z] + sm.attn.sM[3][row][z];
    M1p[((size_t)cb * N2P + i0 + row) * DZ + z] = (__bf16)m;
  }
}

__device__ __forceinline__ void do_final(SMem& sm, int vb, int tid,
    const float* __restrict__ tg_X, const float* __restrict__ tg_delay,
    const float* __restrict__ Zp, const __bf16* __restrict__ M1p,
    const float* __restrict__ rp,
    const float* __restrict__ W1, const float* __restrict__ b1,
    const float* __restrict__ W2, const float* __restrict__ b2,
    const float* __restrict__ Wg, const float* __restrict__ bg,
    const float* __restrict__ Wa, const float* __restrict__ ba,
    const float* __restrict__ g2p, const float* __restrict__ g3p,
    const float* __restrict__ ap, const float* __restrict__ bp,
    float* __restrict__ out) {
  const int z = tid & 31, li = tid >> 5;
  const int i = vb * 8 + li;
  if (tid < 32) {
    float t0 = 0.f, t1 = 0.f;
#pragma unroll
    for (int cc = 0; cc < NRED; ++cc) {
      t0 += rp[cc * 66 + tid];
      t1 += rp[cc * 66 + 32 + tid];
    }
    sm.fin.s_rsum[tid] = t0; sm.fin.s_dv[tid] = t1;
  } else if (tid == 32) {
    float d = 0.f;
#pragma unroll
    for (int cc = 0; cc < NRED; ++cc) d += rp[cc * 66 + 64];
    sm.fin.s_ds[0] = d;
  }
  __syncthreads();
  if (li == 0) {
    const float r0 = sm.fin.s_rsum[z] * (1.f / (float)N1);
    sm.fin.s_r0[z] = r0;
    sm.fin.s_tmp[z] = (r0 + sm.fin.s_dv[z]) / (1.f + sm.fin.s_ds[0] + 1e-12f);
  }
  __syncthreads();
  if (li == 0) {
    float acc = b1[z];
#pragma unroll
    for (int k = 0; k < DZ; ++k) acc += W1[z * DZ + k] * sm.fin.s_tmp[k];
    sm.fin.s_r1[z] = acc;
  }
  const float a = ap[0], b = bp[0], g2 = g2p[0], g3 = g3p[0];
  const float td = tg_delay[i];
  const float rt0 = __expf(-g2 * (a * td + b));
  const float rt1 = __expf(-g3 * (a * td + b));
  const float tgx = (z < DIN) ? tg_X[i * DIN + z] : 0.f;
  float Zt = (float)N1, m1 = 0.f;
#pragma unroll
  for (int cc = 0; cc < NCHB; ++cc) {
    Zt += Zp[cc * N2P + i];
    m1 += (float)M1p[((size_t)cc * N2P + i) * DZ + z];
  }
  const float rsum_z = sm.fin.s_rsum[z];
  const float aggsum = rsum_z + (m1 + rsum_z) / Zt;
  const float sum_t = (float)N1 + 1.f;
  const float deg = 1.f + sum_t + rt0 + 1e-12f;
  __syncthreads();
  sm.fin.s_a[li][z] = (tgx + aggsum + rt0 * sm.fin.s_r0[z]) / deg;
  __syncthreads();
  float t1v = b1[z];
#pragma unroll
  for (int k = 0; k < DZ; ++k) t1v += W1[z * DZ + k] * sm.fin.s_a[li][k];
  sm.fin.s_t1[li][z] = t1v;
  __syncthreads();
  sm.fin.s_a[li][z] = (t1v + rt1 * sm.fin.s_r1[z]) / (1.f + rt1 + 1e-12f);
  __syncthreads();
  float t2v = b2[z];
#pragma unroll
  for (int k = 0; k < DZ; ++k) t2v += W2[z * DZ + k] * sm.fin.s_a[li][k];
  sm.fin.s_t2[li][z] = t2v;
  __syncthreads();
  if (z < 5) {
    float og = bg[z];
#pragma unroll
    for (int k = 0; k < DZ; ++k) og += Wg[z * 64 + k] * sm.fin.s_t1[li][k];
#pragma unroll
    for (int k = 0; k < DZ; ++k) og += Wg[z * 64 + DZ + k] * sm.fin.s_t2[li][k];
    if (z == 0)      out[2 * i] = og;
    else if (z == 1) out[2 * i + 1] = og;
    else if (z == 2) out[10000 + i] = softplus_f(og);
    else if (z == 3) out[15000 + i] = softplus_f(og) + 1.f;
    else             out[20000 + i] = softplus_f(og);
  } else if (z >= 8 && z < 13) {
    const int hh = z - 8;
    float oa = ba[hh];
#pragma unroll
    for (int k = 0; k < DIN; ++k) oa += Wa[hh * DIN + k] * tg_X[i * DIN + k];
    if (hh == 0)      out[25000 + 2 * i] = oa;
    else if (hh == 1) out[25000 + 2 * i + 1] = oa;
    else if (hh == 2) out[35000 + i] = softplus_f(oa);
    else if (hh == 3) out[40000 + i] = softplus_f(oa) + 1.f;
    else              out[45000 + i] = softplus_f(oa);
  }
}

// ---------------- fused cooperative kernel ----------------

__global__ __launch_bounds__(256, 4) void k_fused(
    const float* __restrict__ lm_X, const float* __restrict__ lm_Y,
    const float* __restrict__ tg_X, const float* __restrict__ lm_delay,
    const float* __restrict__ tg_delay,
    const float* __restrict__ Wq, const float* __restrict__ Wk,
    const float* __restrict__ g1p, const float* __restrict__ g2p,
    const float* __restrict__ g3p, const float* __restrict__ ap,
    const float* __restrict__ bp,
    const float* __restrict__ W1, const float* __restrict__ b1,
    const float* __restrict__ W2, const float* __restrict__ b2,
    const float* __restrict__ Wg, const float* __restrict__ bg,
    const float* __restrict__ Wa, const float* __restrict__ ba,
    __bf16* __restrict__ Kb, __bf16* __restrict__ Ff,
    __bf16* __restrict__ Qb, float* __restrict__ Zp,
    __bf16* __restrict__ M1p, float* __restrict__ rp,
    float* __restrict__ out) {
  cg::grid_group grid = cg::this_grid();
  __shared__ SMem sm;
  const int tid = threadIdx.x;
  for (int vb = blockIdx.x; vb < NPREP; vb += (int)gridDim.x) {
    do_prep(sm, vb, tid, lm_X, lm_Y, tg_X, lm_delay, Wq, Wk, g1p, ap, bp,
            Kb, Ff, Qb, rp);
    __syncthreads();
  }
  grid.sync();
  for (int vb = blockIdx.x; vb < NATTN; vb += (int)gridDim.x) {
    do_attn(sm, vb, tid, Kb, Ff, Qb, Zp, M1p);
    __syncthreads();
  }
  grid.sync();
  for (int vb = blockIdx.x; vb < NFIN; vb += (int)gridDim.x) {
    do_final(sm, vb, tid, tg_X, tg_delay, Zp, M1p, rp, W1, b1, W2, b2,
             Wg, bg, Wa, ba, g2p, g3p, ap, bp, out);
    __syncthreads();
  }
}

// ---------------- standalone fallback kernels ----------------

__global__ __launch_bounds__(256) void k_prep_s(
    const float* __restrict__ lm_X, const float* __restrict__ lm_Y,
    const float* __restrict__ tg_X, const float* __restrict__ lm_delay,
    const float* __restrict__ Wq, const float* __restrict__ Wk,
    const float* __restrict__ g1p, const float* __restrict__ ap,
    const float* __restrict__ bp,
    __bf16* __restrict__ Kb, __bf16* __restrict__ Ff,
    __bf16* __restrict__ Qb, float* __restrict__ rp) {
  __shared__ SMem sm;
  do_prep(sm, blockIdx.x, threadIdx.x, lm_X, lm_Y, tg_X, lm_delay, Wq, Wk,
          g1p, ap, bp, Kb, Ff, Qb, rp);
}

__global__ __launch_bounds__(256) void k_attn_s(
    const __bf16* __restrict__ Kb, const __bf16* __restrict__ Ff,
    const __bf16* __restrict__ Qb, float* __restrict__ Zp,
    __bf16* __restrict__ M1p) {
  __shared__ SMem sm;
  do_attn(sm, blockIdx.x, threadIdx.x, Kb, Ff, Qb, Zp, M1p);
}

__global__ __launch_bounds__(256) void k_final_s(
    const float* __restrict__ tg_X, const float* __restrict__ tg_delay,
    const float* __restrict__ Zp, const __bf16* __restrict__ M1p,
    const float* __restrict__ rp,
    const float* __restrict__ W1, const float* __restrict__ b1,
    const float* __restrict__ W2, const float* __restrict__ b2,
    const float* __restrict__ Wg, const float* __restrict__ bg,
    const float* __restrict__ Wa, const float* __restrict__ ba,
    const float* __restrict__ g2p, const float* __restrict__ g3p,
    const float* __restrict__ ap, const float* __restrict__ bp,
    float* __restrict__ out) {
  __shared__ SMem sm;
  do_final(sm, blockIdx.x, threadIdx.x, tg_X, tg_delay, Zp, M1p, rp,
           W1, b1, W2, b2, Wg, bg, Wa, ba, g2p, g3p, ap, bp, out);
}

extern "C" void kernel_launch(void* const* d_in, const int* in_sizes, int n_in,
                              void* d_out, int out_size, void* d_ws, size_t ws_size,
                              hipStream_t stream) {
  const float* lm_X    = (const float*)d_in[0];
  const float* lm_Y    = (const float*)d_in[1];
  const float* tg_X    = (const float*)d_in[2];
  const float* lm_delay= (const float*)d_in[4];
  const float* tg_delay= (const float*)d_in[5];
  const float* Wq      = (const float*)d_in[6];
  const float* Wk      = (const float*)d_in[7];
  const float* g1      = (const float*)d_in[9];
  const float* g2      = (const float*)d_in[10];
  const float* g3      = (const float*)d_in[11];
  const float* al      = (const float*)d_in[12];
  const float* be      = (const float*)d_in[13];
  const float* W1      = (const float*)d_in[14];
  const float* b1      = (const float*)d_in[15];
  const float* W2      = (const float*)d_in[16];
  const float* b2      = (const float*)d_in[17];
  const float* Wg      = (const float*)d_in[18];
  const float* bg      = (const float*)d_in[19];
  const float* Wa      = (const float*)d_in[20];
  const float* ba      = (const float*)d_in[21];
  float* out = (float*)d_out;
  char* ws   = (char*)d_ws;

  __bf16* Kb   = (__bf16*)(ws + OFFB_K);
  __bf16* Ff   = (__bf16*)(ws + OFFB_FF);
  __bf16* Qb   = (__bf16*)(ws + OFFB_Q);
  float*  Zp   = (float*)(ws + OFFB_ZP);
  __bf16* M1p  = (__bf16*)(ws + OFFB_M1);
  float*  rp   = (float*)(ws + OFFB_RP);

  // size the cooperative grid from the runtime's own occupancy calc
  int nblk = 0;
  hipError_t oerr = hipOccupancyMaxActiveBlocksPerMultiprocessor(
      &nblk, reinterpret_cast<const void*>(&k_fused), 256, 0);
  int ncu = 0;
  hipDeviceGetAttribute(&ncu, hipDeviceAttributeMultiprocessorCount, 0);
  long cap = (long)nblk * (long)ncu;
  int gridN = (cap < (long)GRID_MAX) ? (int)cap : GRID_MAX;

  hipError_t lerr = hipErrorUnknown;
  if (oerr == hipSuccess && gridN >= 1) {
    void* args[] = {
      (void*)&lm_X, (void*)&lm_Y, (void*)&tg_X, (void*)&lm_delay, (void*)&tg_delay,
      (void*)&Wq, (void*)&Wk, (void*)&g1, (void*)&g2, (void*)&g3,
      (void*)&al, (void*)&be, (void*)&W1, (void*)&b1, (void*)&W2, (void*)&b2,
      (void*)&Wg, (void*)&bg, (void*)&Wa, (void*)&ba,
      (void*)&Kb, (void*)&Ff, (void*)&Qb, (void*)&Zp, (void*)&M1p, (void*)&rp,
      (void*)&out
    };
    lerr = hipLaunchCooperativeKernel((const void*)k_fused, dim3(gridN),
                                      dim3(256), args, 0, stream);
  }
  if (lerr != hipSuccess) {
    // fallback: proven 3-kernel path (identical device code)
    hipLaunchKernelGGL(k_prep_s, dim3(NPREP), dim3(256), 0, stream,
                       lm_X, lm_Y, tg_X, lm_delay, Wq, Wk, g1, al, be,
                       Kb, Ff, Qb, rp);
    hipLaunchKernelGGL(k_attn_s, dim3(NATTN), dim3(256), 0, stream,
                       Kb, Ff, Qb, Zp, M1p);
    hipLaunchKernelGGL(k_final_s, dim3(NFIN), dim3(256), 0, stream,
                       tg_X, tg_delay, Zp, M1p, rp,
                       W1, b1, W2, b2, Wg, bg, Wa, ba, g2, g3, al, be, out);
  }
}